// Round 4
// baseline (306.801 us; speedup 1.0000x reference)
//
#include <hip/hip_runtime.h>
#include <hip/hip_bf16.h>
#include <math.h>

// ---------------------------------------------------------------------------
// Round 4: same validated 16x16x32-MFMA core (absmax 0.125), restructured to
// shorten the per-tile serial chain and raise CU-level overlap:
//   - 4 blocks/CU (launch_bounds(256,4), grid 1024) -> 16 waves/CU.
//   - NO global atomics, NO S5 barrier: each wave stores its layer-4 partial
//     sums to a per-wave global slice fb[4][M]; a tiny reduce kernel sums the
//     4 slices, applies elu+1, cc_w, (xmax-x0)/2 and writes out[b].
//     Barriers/tile: 2 (y1-ready, y2-ready). Atomic-drain at barrier: gone.
//   - hpart kernel: W1 row in 64 VGPRs (coalesced global), h staged once in
//     LDS (b128 reads) -> VALU-bound, ~3 us (was ~15-20 us ds_read_b32-bound).
//   - prep tables: exact-period int reduction + __cosf (err ~1e-7, negligible
//     against the 0.125-vs-0.4725 margin).
// ws floats: [0..50]=cc_w [64..114]=steps [128]=xmax
//            [256..)=hpart[16384][128]  [2097408..)=fb[4][835584]
// ---------------------------------------------------------------------------

#define B_N    16384
#define KQ     51
#define HD     128
#define IND    64
#define M_TOT  (B_N * KQ)        // 835584
#define TS     64                // samples per tile
#define NTILES (M_TOT / TS)      // 13056
#define GRID_MAIN 1024           // 4 blocks/CU; 12-13 tiles/block

#define WS_CCW    0
#define WS_STEPS  64
#define WS_XMAX   128
#define WS_HPART  256
#define WS_FB     (WS_HPART + B_N * HD)          // 2097408
#define WS_NEED_BIG ((size_t)(WS_FB + 4 * M_TOT) * 4)

typedef __attribute__((ext_vector_type(8))) short short8;
typedef __attribute__((ext_vector_type(4))) float f32x4;

__device__ __forceinline__ unsigned short f2bf(float f) {
    __hip_bfloat16 t = __float2bfloat16(f);
    return *reinterpret_cast<unsigned short*>(&t);
}

#if defined(__gfx950__) && defined(__has_builtin)
#if __has_builtin(__builtin_amdgcn_cvt_pk_bf16_f32)
#define HAVE_PK_BF16 1
#endif
#endif

__device__ __forceinline__ unsigned pk_bf16(float lo, float hi) {
#ifdef HAVE_PK_BF16
    typedef __attribute__((ext_vector_type(2))) __bf16 bfv2;
    bfv2 r = __builtin_amdgcn_cvt_pk_bf16_f32(lo, hi);
    return *reinterpret_cast<unsigned*>(&r);
#else
    return (unsigned)f2bf(lo) | ((unsigned)f2bf(hi) << 16);
#endif
}

// ---------------- prep: CC tables (fast cos), xmax, zero d_out --------------
__global__ void umnn_prep(const float* __restrict__ x, float* __restrict__ out,
                          float* __restrict__ ws)
{
    const int tid = threadIdx.x;
    const int bid = blockIdx.x;
    if (bid == 0) {
        if (tid <= KQ - 1) {
            const int j = tid;
            const float pi50 = 0.06283185307179586f;     // pi/50
            ws[WS_STEPS + j] = __cosf((float)j * pi50);
            float s = 0.0f;
            for (int i = 0; i <= 50; i += 2) {           // odd i: W=0
                float Wi = (i == 0) ? 1.0f : 2.0f / (1.0f - (float)(i * i));
                float lam;
                if (j == 0) lam = 0.5f;
                else {
                    int m = (i * j) % 100;               // cos period = 100 units
                    lam = __cosf((float)m * pi50);
                    if (j == 50) lam *= 0.5f;
                }
                s += (lam * 0.04f) * Wi;                 // *2/50
            }
            ws[WS_CCW + j] = s;
        }
    } else if (bid == 1) {
        __shared__ float red[256];
        float mx = -1e30f;
        for (int i = tid; i < B_N; i += 256) mx = fmaxf(mx, x[i]);
        red[tid] = mx;
        __syncthreads();
        for (int s2 = 128; s2 > 0; s2 >>= 1) {
            if (tid < s2) red[tid] = fmaxf(red[tid], red[tid + s2]);
            __syncthreads();
        }
        if (tid == 0) ws[WS_XMAX] = red[0] + 10.0f;
    } else {
        int i = (bid - 2) * 256 + tid;
        if (i < B_N) out[i] = 0.0f;                      // needed by SMALL path
    }
}

// ---------------- hpart: [16384][128] fp32 into ws --------------------------
// 512 blocks x 32 b-rows. W1 row (incl. x col) in 64 VGPRs from global;
// h rows staged once in LDS, read as b128. Same ascending-d fma order as r1.
__launch_bounds__(256, 4)
__global__ void umnn_hpart(const float* __restrict__ h, const float* __restrict__ W1,
                           const float* __restrict__ b1, float* __restrict__ ws)
{
    __shared__ __align__(16) float hsh[32][IND];        // [r][d], d<63 used
    float* hpartG = ws + WS_HPART;
    const int tid = threadIdx.x;
    const int b32 = blockIdx.x * 32;

    for (int i = tid; i < 32 * (IND - 1); i += 256) {
        int r = i / 63, d = i - r * 63;
        hsh[r][d] = h[b32 * (IND - 1) + i];
    }
    const int n = tid & 127, bloc = tid >> 7;
    float w1r[IND];
    #pragma unroll
    for (int j = 0; j < IND / 4; ++j) {
        f32x4 v = *(const f32x4*)(W1 + n * IND + j * 4);
        w1r[j * 4] = v[0]; w1r[j * 4 + 1] = v[1];
        w1r[j * 4 + 2] = v[2]; w1r[j * 4 + 3] = v[3];
    }
    const float b1v = b1[n];
    __syncthreads();

    #pragma unroll 2
    for (int it = 0; it < 16; ++it) {
        int r = it * 2 + bloc;
        float acc = b1v;
        #pragma unroll
        for (int d = 0; d < IND - 1; ++d)
            acc = fmaf(w1r[1 + d], hsh[r][d], acc);
        hpartG[(b32 + r) * HD + n] = acc;
    }
}

// ---------------- main MFMA kernel ------------------------------------------
template<bool BIG>
__launch_bounds__(256, 4)
__global__ void umnn_main(const float* __restrict__ x,  const float* __restrict__ h,
                          const float* __restrict__ W1, const float* __restrict__ b1,
                          const float* __restrict__ W2, const float* __restrict__ b2,
                          const float* __restrict__ W3, const float* __restrict__ b3,
                          const float* __restrict__ W4, const float* __restrict__ b4,
                          float* __restrict__ out, float* __restrict__ ws)
{
    __shared__ __align__(16) char  y1s[TS * 256];   // 64 rows x 128 bf16, swizzled
    __shared__ __align__(16) char  y2s[TS * 256];
    __shared__ float partS4[4][TS];                 // SMALL path only
    __shared__ __align__(16) float hpS[3 * HD];     // SMALL path only
    __shared__ float sSteps[64], sCcw[64];

    const int tid  = threadIdx.x;
    const int w    = tid >> 6;
    const int lane = tid & 63;
    const int q    = lane >> 4;
    const int lm   = lane & 15;
    const int swz  = lm & 7;
    const int n8   = tid & 15;          // phase-A feature octet
    const int ms   = tid >> 4;          // phase-A sample within 16-group

    if (tid < KQ) { sSteps[tid] = ws[WS_STEPS + tid]; sCcw[tid] = ws[WS_CCW + tid]; }

    const float xmax = ws[WS_XMAX];
    const float b4v  = b4[0];
    float* fbW = ws + WS_FB + w * M_TOT;            // this wave's partial slice

    float w1x[8];
    #pragma unroll
    for (int j = 0; j < 8; ++j) w1x[j] = W1[(n8 * 8 + j) * IND];

    short8 W2A[2][4], W3A[2][4];
    f32x4  b2r[2], b3r[2], W4r[2];
    #pragma unroll
    for (int ntl = 0; ntl < 2; ++ntl) {
        const int nf = (w * 2 + ntl) * 16 + lm;
        #pragma unroll
        for (int kk = 0; kk < 4; ++kk) {
            const float* p2 = W2 + nf * HD + kk * 32 + q * 8;
            const float* p3 = W3 + nf * HD + kk * 32 + q * 8;
            short8 a2, a3;
            #pragma unroll
            for (int j = 0; j < 8; ++j) {
                a2[j] = (short)f2bf(p2[j]);
                a3[j] = (short)f2bf(p3[j]);
            }
            W2A[ntl][kk] = a2; W3A[ntl][kk] = a3;
        }
        const int nb0 = (w * 2 + ntl) * 16 + q * 4;
        b2r[ntl] = *(const f32x4*)(b2 + nb0);
        b3r[ntl] = *(const f32x4*)(b3 + nb0);
        W4r[ntl] = *(const f32x4*)(W4 + nb0);
    }
    __syncthreads();

    for (int tile = blockIdx.x; tile < NTILES; tile += GRID_MAIN) {
        const int g0 = tile * TS;
        const int b0 = g0 / KQ;
        const float* hpB;
        if constexpr (BIG) {
            hpB = ws + WS_HPART + b0 * HD + n8 * 8;
        } else {
            const int nb = (g0 + TS - 1) / KQ - b0 + 1;
            for (int idx = tid; idx < nb * HD; idx += 256) {
                int r = idx >> 7, n = idx & 127;
                const float* hr = h + (b0 + r) * (IND - 1);
                const float* wr = W1 + n * IND + 1;
                float acc = b1[n];
                #pragma unroll
                for (int d = 0; d < IND - 1; ++d) acc = fmaf(wr[d], hr[d], acc);
                hpS[idx] = acc;
            }
            __syncthreads();
            hpB = hpS + n8 * 8;
        }

        // ---- phase A: Y1 -> LDS (bf16, sample-major, swizzled b128) ----
        {
            const int phys = (n8 ^ (ms & 7)) << 4;
            #pragma unroll
            for (int it = 0; it < 4; ++it) {
                int m  = ms + it * 16;
                int g  = g0 + m;
                int bb = (int)((unsigned)g / KQ);
                float x0 = x[bb];
                float X  = fmaf((xmax - x0) * 0.5f, sSteps[g - bb * KQ] + 1.0f, x0);
                const float* hp = hpB + (bb - b0) * HD;
                f32x4 ha = *(const f32x4*)hp;
                f32x4 hb = *(const f32x4*)(hp + 4);
                unsigned u0 = pk_bf16(fmaxf(fmaf(X, w1x[0], ha[0]), 0.f),
                                      fmaxf(fmaf(X, w1x[1], ha[1]), 0.f));
                unsigned u1 = pk_bf16(fmaxf(fmaf(X, w1x[2], ha[2]), 0.f),
                                      fmaxf(fmaf(X, w1x[3], ha[3]), 0.f));
                unsigned u2 = pk_bf16(fmaxf(fmaf(X, w1x[4], hb[0]), 0.f),
                                      fmaxf(fmaf(X, w1x[5], hb[1]), 0.f));
                unsigned u3 = pk_bf16(fmaxf(fmaf(X, w1x[6], hb[2]), 0.f),
                                      fmaxf(fmaf(X, w1x[7], hb[3]), 0.f));
                *(int4*)(y1s + m * 256 + phys) = make_int4(u0, u1, u2, u3);
            }
        }
        __syncthreads();                               // S3: y1 ready

        // ---- layer 2 ----
        f32x4 C[2][4];
        #pragma unroll
        for (int ntl = 0; ntl < 2; ++ntl)
            #pragma unroll
            for (int mt = 0; mt < 4; ++mt) C[ntl][mt] = b2r[ntl];
        #pragma unroll
        for (int kk = 0; kk < 4; ++kk)
            #pragma unroll
            for (int mt = 0; mt < 4; ++mt) {
                short8 Bf = *(const short8*)(y1s + (mt * 16 + lm) * 256
                                             + ((((kk << 2) + q) ^ swz) << 4));
                C[0][mt] = __builtin_amdgcn_mfma_f32_16x16x32_bf16(W2A[0][kk], Bf, C[0][mt], 0, 0, 0);
                C[1][mt] = __builtin_amdgcn_mfma_f32_16x16x32_bf16(W2A[1][kk], Bf, C[1][mt], 0, 0, 0);
            }
        #pragma unroll
        for (int ntl = 0; ntl < 2; ++ntl) {
            const int cch  = ((w * 2 + ntl) << 1) + (q >> 1);
            const int off8 = (q & 1) << 3;
            #pragma unroll
            for (int mt = 0; mt < 4; ++mt) {
                f32x4 v = C[ntl][mt];
                unsigned lo = pk_bf16(fmaxf(v[0], 0.f), fmaxf(v[1], 0.f));
                unsigned hi = pk_bf16(fmaxf(v[2], 0.f), fmaxf(v[3], 0.f));
                *(int2*)(y2s + (mt * 16 + lm) * 256 + ((cch ^ swz) << 4) + off8)
                    = make_int2((int)lo, (int)hi);
            }
        }
        __syncthreads();                               // S4: y2 ready

        // ---- layer 3 ----
        #pragma unroll
        for (int ntl = 0; ntl < 2; ++ntl)
            #pragma unroll
            for (int mt = 0; mt < 4; ++mt) C[ntl][mt] = b3r[ntl];
        #pragma unroll
        for (int kk = 0; kk < 4; ++kk)
            #pragma unroll
            for (int mt = 0; mt < 4; ++mt) {
                short8 Bf = *(const short8*)(y2s + (mt * 16 + lm) * 256
                                             + ((((kk << 2) + q) ^ swz) << 4));
                C[0][mt] = __builtin_amdgcn_mfma_f32_16x16x32_bf16(W3A[0][kk], Bf, C[0][mt], 0, 0, 0);
                C[1][mt] = __builtin_amdgcn_mfma_f32_16x16x32_bf16(W3A[1][kk], Bf, C[1][mt], 0, 0, 0);
            }

        // ---- layer 4 partials ----
        #pragma unroll
        for (int mt = 0; mt < 4; ++mt) {
            float p = 0.f;
            #pragma unroll
            for (int ntl = 0; ntl < 2; ++ntl) {
                f32x4 v = C[ntl][mt];
                p = fmaf(fmaxf(v[0], 0.f), W4r[ntl][0], p);
                p = fmaf(fmaxf(v[1], 0.f), W4r[ntl][1], p);
                p = fmaf(fmaxf(v[2], 0.f), W4r[ntl][2], p);
                p = fmaf(fmaxf(v[3], 0.f), W4r[ntl][3], p);
            }
            p += __shfl_xor(p, 16);
            p += __shfl_xor(p, 32);
            if constexpr (BIG) {
                if (lane < 16) fbW[g0 + mt * 16 + lane] = p;   // 64B qtr-wave store
            } else {
                if (lane < 16) partS4[w][mt * 16 + lane] = p;
            }
        }
        if constexpr (!BIG) {
            __syncthreads();
            if (tid < TS) {
                int g  = g0 + tid;
                int bb = (int)((unsigned)g / KQ);
                int k  = g - bb * KQ;
                float x0 = x[bb];
                float y4 = partS4[0][tid] + partS4[1][tid] + partS4[2][tid]
                         + partS4[3][tid] + b4v;
                float f  = (y4 > 0.f) ? (y4 + 1.f) : __expf(y4);
                atomicAdd(&out[bb], f * (sCcw[k] * (xmax - x0) * 0.5f));
            }
        }
    }
}

// ---------------- reduce: out[b] from 4 fb slices (BIG path) ----------------
__launch_bounds__(256)
__global__ void umnn_reduce(const float* __restrict__ x, const float* __restrict__ b4,
                            float* __restrict__ out, const float* __restrict__ ws)
{
    const int tid  = threadIdx.x;
    const int w    = tid >> 6;
    const int lane = tid & 63;
    const int b    = blockIdx.x * 4 + w;
    const float xmax = ws[WS_XMAX];
    const float b4v  = b4[0];
    const float* fb  = ws + WS_FB;

    float t = 0.f;
    if (lane < KQ) {
        int g = b * KQ + lane;
        float s = fb[g] + fb[M_TOT + g] + fb[2 * M_TOT + g] + fb[3 * M_TOT + g];
        float y4 = s + b4v;
        float f  = (y4 > 0.f) ? (y4 + 1.f) : __expf(y4);
        t = f * ws[WS_CCW + lane];
    }
    #pragma unroll
    for (int d = 32; d > 0; d >>= 1) t += __shfl_xor(t, d);
    if (lane == 0) out[b] = t * (xmax - x[b]) * 0.5f;
}

// ---------------------------------------------------------------------------
extern "C" void kernel_launch(void* const* d_in, const int* in_sizes, int n_in,
                              void* d_out, int out_size, void* d_ws, size_t ws_size,
                              hipStream_t stream)
{
    const float* x  = (const float*)d_in[0];
    const float* h  = (const float*)d_in[1];
    const float* W1 = (const float*)d_in[2];
    const float* b1 = (const float*)d_in[3];
    const float* W2 = (const float*)d_in[4];
    const float* b2 = (const float*)d_in[5];
    const float* W3 = (const float*)d_in[6];
    const float* b3 = (const float*)d_in[7];
    const float* W4 = (const float*)d_in[8];
    const float* b4 = (const float*)d_in[9];
    float* out = (float*)d_out;
    float* ws  = (float*)d_ws;

    umnn_prep<<<2 + (B_N + 255) / 256, 256, 0, stream>>>(x, out, ws);

    if (ws_size >= WS_NEED_BIG) {
        umnn_hpart<<<B_N / 32, 256, 0, stream>>>(h, W1, b1, ws);
        umnn_main<true><<<GRID_MAIN, 256, 0, stream>>>(x, h, W1, b1, W2, b2, W3, b3,
                                                       W4, b4, out, ws);
        umnn_reduce<<<B_N / 4, 256, 0, stream>>>(x, b4, out, ws);
    } else {
        umnn_main<false><<<GRID_MAIN, 256, 0, stream>>>(x, h, W1, b1, W2, b2, W3, b3,
                                                        W4, b4, out, ws);
    }
}

// Round 5
// 247.583 us; speedup vs baseline: 1.2392x; 1.2392x over previous
//
#include <hip/hip_runtime.h>
#include <hip/hip_bf16.h>
#include <math.h>

// ---------------------------------------------------------------------------
// Round 5: ONE fused persistent kernel (plus a d_out memset). Round-4 showed
// (a) 142 us of multi-kernel overhead and (b) fb/hpart global traffic blowing
// L2 (FETCH 10.7 MB -> 306 MB). Fix: block-local everything.
//   - grid 768 (3 blocks/CU exactly), 17 CONTIGUOUS tiles per block
//     (13056 = 768*17, zero tail).
//   - block computes its own <=23 hpart rows ONCE into LDS (~750 FMA/thread,
//     amortized ~46 cyc/tile), its own CC tables + xmax (x is L2-resident).
//   - per-b accumulation in LDS zLoc[] via wave-0 segmented shuffle-reduce;
//     <=23 global atomics per BLOCK (boundary rows shared by 2 blocks).
//   - validated MFMA core (16x16x32 bf16, weights-as-A reg-resident,
//     activations-as-B sample-major swizzled LDS) untouched: absmax 0.125.
//   - 3 barriers/tile; no global scratch: d_ws unused.
// ---------------------------------------------------------------------------

#define B_N    16384
#define KQ     51
#define HD     128
#define IND    64
#define M_TOT  (B_N * KQ)        // 835584
#define TS     64                // samples per tile
#define NTILES (M_TOT / TS)      // 13056
#define GRID_MAIN 768            // 3 blocks/CU * 256 CUs
#define TPB    17                // contiguous tiles per block (exact)
#define MAXR   24                // max hpart rows a block can touch (<=23)

typedef __attribute__((ext_vector_type(8))) short short8;
typedef __attribute__((ext_vector_type(4))) float f32x4;

__device__ __forceinline__ unsigned short f2bf(float f) {
    __hip_bfloat16 t = __float2bfloat16(f);
    return *reinterpret_cast<unsigned short*>(&t);
}

#if defined(__gfx950__) && defined(__has_builtin)
#if __has_builtin(__builtin_amdgcn_cvt_pk_bf16_f32)
#define HAVE_PK_BF16 1
#endif
#endif

__device__ __forceinline__ unsigned pk_bf16(float lo, float hi) {
#ifdef HAVE_PK_BF16
    typedef __attribute__((ext_vector_type(2))) __bf16 bfv2;
    bfv2 r = __builtin_amdgcn_cvt_pk_bf16_f32(lo, hi);
    return *reinterpret_cast<unsigned*>(&r);
#else
    return (unsigned)f2bf(lo) | ((unsigned)f2bf(hi) << 16);
#endif
}

__launch_bounds__(256, 3)
__global__ void umnn_fused(const float* __restrict__ x,  const float* __restrict__ h,
                           const float* __restrict__ W1, const float* __restrict__ b1,
                           const float* __restrict__ W2, const float* __restrict__ b2,
                           const float* __restrict__ W3, const float* __restrict__ b3,
                           const float* __restrict__ W4, const float* __restrict__ b4,
                           float* __restrict__ out)
{
    __shared__ __align__(16) char  y1s[TS * 256];   // 16 KB, swizzled bf16
    __shared__ __align__(16) char  y2s[TS * 256];   // 16 KB
    __shared__ __align__(16) float hpL[MAXR * HD];  // 12 KB block-local hpart
    __shared__ float xL[MAXR];                      // x0 per local b row
    __shared__ float zLoc[MAXR];                    // sum_k f*ccw per local b
    __shared__ float partS4[4][TS];                 // layer-4 wave partials
    __shared__ float sSteps[KQ], sCcw[KQ];
    __shared__ float red4[4];

    const int tid  = threadIdx.x;
    const int w    = tid >> 6;
    const int lane = tid & 63;
    const int q    = lane >> 4;
    const int lm   = lane & 15;
    const int swz  = lm & 7;
    const int n8   = tid & 15;          // phase-A feature octet
    const int ms   = tid >> 4;          // phase-A sample-within-16

    const int t0     = blockIdx.x * TPB;
    const int gB0    = t0 * TS;
    const int bStart = gB0 / KQ;
    const int nRows  = (gB0 + TPB * TS - 1) / KQ - bStart + 1;   // <= 23

    // ---- per-block CC tables (same formula/precision as r4 - validated) ----
    if (tid < KQ) {
        const int j = tid;
        const float pi50 = 0.06283185307179586f;
        sSteps[j] = __cosf((float)j * pi50);
        float s = 0.0f;
        for (int i = 0; i <= 50; i += 2) {
            float Wi = (i == 0) ? 1.0f : 2.0f / (1.0f - (float)(i * i));
            float lam;
            if (j == 0) lam = 0.5f;
            else {
                int mp = (i * j) % 100;
                lam = __cosf((float)mp * pi50);
                if (j == 50) lam *= 0.5f;
            }
            s += (lam * 0.04f) * Wi;
        }
        sCcw[j] = s;
    }
    // ---- per-block xmax (x is 64 KB, L2-resident) ----
    {
        const f32x4* x4 = (const f32x4*)x;
        float mx = -1e30f;
        for (int i = tid; i < B_N / 4; i += 256) {
            f32x4 v = x4[i];
            mx = fmaxf(fmaxf(mx, fmaxf(v[0], v[1])), fmaxf(v[2], v[3]));
        }
        #pragma unroll
        for (int d = 32; d > 0; d >>= 1) mx = fmaxf(mx, __shfl_xor(mx, d));
        if (lane == 0) red4[w] = mx;
    }
    // ---- block-local hpart rows + xL + zLoc init ----
    for (int idx = tid; idx < nRows * HD; idx += 256) {
        int r = idx >> 7, n = idx & 127;
        const float* hr = h + (bStart + r) * (IND - 1);
        const float* wr = W1 + n * IND + 1;
        float acc = b1[n];
        #pragma unroll
        for (int d = 0; d < IND - 1; ++d) acc = fmaf(wr[d], hr[d], acc);
        hpL[idx] = acc;
    }
    if (tid < MAXR) {
        xL[tid]   = (bStart + tid < B_N) ? x[bStart + tid] : 0.0f;
        zLoc[tid] = 0.0f;
    }

    // ---- tile-invariant registers ----
    float w1x[8];
    #pragma unroll
    for (int j = 0; j < 8; ++j) w1x[j] = W1[(n8 * 8 + j) * IND];

    short8 W2A[2][4], W3A[2][4];
    f32x4  b2r[2], b3r[2], W4r[2];
    #pragma unroll
    for (int ntl = 0; ntl < 2; ++ntl) {
        const int nf = (w * 2 + ntl) * 16 + lm;
        #pragma unroll
        for (int kk = 0; kk < 4; ++kk) {
            const float* p2 = W2 + nf * HD + kk * 32 + q * 8;
            const float* p3 = W3 + nf * HD + kk * 32 + q * 8;
            short8 a2, a3;
            #pragma unroll
            for (int j = 0; j < 8; ++j) {
                a2[j] = (short)f2bf(p2[j]);
                a3[j] = (short)f2bf(p3[j]);
            }
            W2A[ntl][kk] = a2; W3A[ntl][kk] = a3;
        }
        const int nb0 = (w * 2 + ntl) * 16 + q * 4;
        b2r[ntl] = *(const f32x4*)(b2 + nb0);
        b3r[ntl] = *(const f32x4*)(b3 + nb0);
        W4r[ntl] = *(const f32x4*)(W4 + nb0);
    }
    const float b4v = b4[0];
    __syncthreads();                                   // tables/hpL/xmax ready
    const float xmax = fmaxf(fmaxf(red4[0], red4[1]),
                             fmaxf(red4[2], red4[3])) + 10.0f;

    for (int tt = 0; tt < TPB; ++tt) {
        const int g0 = (t0 + tt) * TS;

        // ---- phase A: Y1 -> LDS (bf16, sample-major, swizzled b128) ----
        {
            const int phys = (n8 ^ (ms & 7)) << 4;
            #pragma unroll
            for (int it = 0; it < 4; ++it) {
                int m  = ms + it * 16;
                int g  = g0 + m;
                int bb = (int)((unsigned)g / KQ);
                int rl = bb - bStart;
                float x0 = xL[rl];
                float X  = fmaf((xmax - x0) * 0.5f, sSteps[g - bb * KQ] + 1.0f, x0);
                const float* hp = hpL + rl * HD + n8 * 8;
                f32x4 ha = *(const f32x4*)hp;
                f32x4 hb = *(const f32x4*)(hp + 4);
                unsigned u0 = pk_bf16(fmaxf(fmaf(X, w1x[0], ha[0]), 0.f),
                                      fmaxf(fmaf(X, w1x[1], ha[1]), 0.f));
                unsigned u1 = pk_bf16(fmaxf(fmaf(X, w1x[2], ha[2]), 0.f),
                                      fmaxf(fmaf(X, w1x[3], ha[3]), 0.f));
                unsigned u2 = pk_bf16(fmaxf(fmaf(X, w1x[4], hb[0]), 0.f),
                                      fmaxf(fmaf(X, w1x[5], hb[1]), 0.f));
                unsigned u3 = pk_bf16(fmaxf(fmaf(X, w1x[6], hb[2]), 0.f),
                                      fmaxf(fmaf(X, w1x[7], hb[3]), 0.f));
                *(int4*)(y1s + m * 256 + phys) = make_int4(u0, u1, u2, u3);
            }
        }
        __syncthreads();                               // S3: y1 ready

        // ---- layer 2 ----
        f32x4 C[2][4];
        #pragma unroll
        for (int ntl = 0; ntl < 2; ++ntl)
            #pragma unroll
            for (int mt = 0; mt < 4; ++mt) C[ntl][mt] = b2r[ntl];
        #pragma unroll
        for (int kk = 0; kk < 4; ++kk)
            #pragma unroll
            for (int mt = 0; mt < 4; ++mt) {
                short8 Bf = *(const short8*)(y1s + (mt * 16 + lm) * 256
                                             + ((((kk << 2) + q) ^ swz) << 4));
                C[0][mt] = __builtin_amdgcn_mfma_f32_16x16x32_bf16(W2A[0][kk], Bf, C[0][mt], 0, 0, 0);
                C[1][mt] = __builtin_amdgcn_mfma_f32_16x16x32_bf16(W2A[1][kk], Bf, C[1][mt], 0, 0, 0);
            }
        #pragma unroll
        for (int ntl = 0; ntl < 2; ++ntl) {
            const int cch  = ((w * 2 + ntl) << 1) + (q >> 1);
            const int off8 = (q & 1) << 3;
            #pragma unroll
            for (int mt = 0; mt < 4; ++mt) {
                f32x4 v = C[ntl][mt];
                unsigned lo = pk_bf16(fmaxf(v[0], 0.f), fmaxf(v[1], 0.f));
                unsigned hi = pk_bf16(fmaxf(v[2], 0.f), fmaxf(v[3], 0.f));
                *(int2*)(y2s + (mt * 16 + lm) * 256 + ((cch ^ swz) << 4) + off8)
                    = make_int2((int)lo, (int)hi);
            }
        }
        __syncthreads();                               // S4: y2 ready

        // ---- layer 3 ----
        #pragma unroll
        for (int ntl = 0; ntl < 2; ++ntl)
            #pragma unroll
            for (int mt = 0; mt < 4; ++mt) C[ntl][mt] = b3r[ntl];
        #pragma unroll
        for (int kk = 0; kk < 4; ++kk)
            #pragma unroll
            for (int mt = 0; mt < 4; ++mt) {
                short8 Bf = *(const short8*)(y2s + (mt * 16 + lm) * 256
                                             + ((((kk << 2) + q) ^ swz) << 4));
                C[0][mt] = __builtin_amdgcn_mfma_f32_16x16x32_bf16(W3A[0][kk], Bf, C[0][mt], 0, 0, 0);
                C[1][mt] = __builtin_amdgcn_mfma_f32_16x16x32_bf16(W3A[1][kk], Bf, C[1][mt], 0, 0, 0);
            }

        // ---- layer 4 partials ----
        #pragma unroll
        for (int mt = 0; mt < 4; ++mt) {
            float p = 0.f;
            #pragma unroll
            for (int ntl = 0; ntl < 2; ++ntl) {
                f32x4 v = C[ntl][mt];
                p = fmaf(fmaxf(v[0], 0.f), W4r[ntl][0], p);
                p = fmaf(fmaxf(v[1], 0.f), W4r[ntl][1], p);
                p = fmaf(fmaxf(v[2], 0.f), W4r[ntl][2], p);
                p = fmaf(fmaxf(v[3], 0.f), W4r[ntl][3], p);
            }
            p += __shfl_xor(p, 16);
            p += __shfl_xor(p, 32);
            if (lane < 16) partS4[w][mt * 16 + lane] = p;
        }
        __syncthreads();                               // S5: partials ready

        // ---- wave-0 epilogue: elu+1, ccw weight, segmented reduce -> zLoc ----
        if (tid < TS) {
            int g   = g0 + tid;
            int bb  = (int)((unsigned)g / KQ);
            int k   = g - bb * KQ;
            int row = bb - bStart;
            float y4 = partS4[0][tid] + partS4[1][tid] + partS4[2][tid]
                     + partS4[3][tid] + b4v;
            float f  = (y4 > 0.f) ? (y4 + 1.f) : __expf(y4);
            float v  = f * sCcw[k];
            const int rowT0 = (int)((unsigned)g0 / KQ) - bStart;
            const int rowT1 = (int)((unsigned)(g0 + TS - 1) / KQ) - bStart;
            #pragma unroll 3
            for (int bi = 0; bi <= rowT1 - rowT0; ++bi) {
                float t = (row == rowT0 + bi) ? v : 0.f;
                #pragma unroll
                for (int d = 32; d > 0; d >>= 1) t += __shfl_xor(t, d);
                if (tid == 0) zLoc[rowT0 + bi] += t;
            }
        }
        // other waves proceed to next phase A; wave 0 joins at next S3.
    }
    __syncthreads();                                   // zLoc final
    if (tid < nRows)
        atomicAdd(&out[bStart + tid],
                  zLoc[tid] * (xmax - xL[tid]) * 0.5f);
}

// ---------------------------------------------------------------------------
extern "C" void kernel_launch(void* const* d_in, const int* in_sizes, int n_in,
                              void* d_out, int out_size, void* d_ws, size_t ws_size,
                              hipStream_t stream)
{
    const float* x  = (const float*)d_in[0];
    const float* h  = (const float*)d_in[1];
    const float* W1 = (const float*)d_in[2];
    const float* b1 = (const float*)d_in[3];
    const float* W2 = (const float*)d_in[4];
    const float* b2 = (const float*)d_in[5];
    const float* W3 = (const float*)d_in[6];
    const float* b3 = (const float*)d_in[7];
    const float* W4 = (const float*)d_in[8];
    const float* b4 = (const float*)d_in[9];
    float* out = (float*)d_out;

    hipMemsetAsync(out, 0, (size_t)B_N * sizeof(float), stream);
    umnn_fused<<<GRID_MAIN, 256, 0, stream>>>(x, h, W1, b1, W2, b2, W3, b3,
                                              W4, b4, out);
}

// Round 6
// 211.081 us; speedup vs baseline: 1.4535x; 1.1729x over previous
//
#include <hip/hip_runtime.h>
#include <hip/hip_bf16.h>
#include <math.h>

// ---------------------------------------------------------------------------
// Round 6: zero-barrier-per-tile, register-resident restructure.
// Evidence from r2-r5: per-CU tile throughput constant (~8-9k cyc/tile)
// across occupancy 2->4 blocks/CU and barriers 5->3  => saturated shared
// resource = LDS pipe + phase-barrier serialization. This kernel cuts LDS
// wave-ops/tile ~3x and removes ALL per-tile barriers:
//   - 512 blocks x 128 threads (2 waves). Wave owns 16 complete b-rows
//     (816 samples = 51 tiles of 16). No cross-wave/cross-block sharing.
//   - Y1 built directly in MFMA-B-fragment registers (phase-A mapping == B
//     layout): y1s LDS buffer deleted.
//   - W2,W3 A-frags register-resident per wave (8nt x 4kk each, ~256 regs ->
//     unified VGPR/AGPR file, launch_bounds(128,1), 1 wave/SIMD).
//   - Y2: wave-private LDS round-trip (8 b64 w + 4 b128 r), no barrier.
//   - layer4+elu+ccw per wave; per-row sums in wave-private LDS; plain
//     global stores to out (all rows covered -> no memset, no atomics).
//   - 2 barriers TOTAL per kernel (setup only).
// Numerics identical to validated r2-r5 chain (absmax 0.125 vs thr 0.4725).
// ---------------------------------------------------------------------------

#define B_N    16384
#define KQ     51
#define HD     128
#define IND    64
#define BLK    128               // 2 waves
#define GRID   512
#define RPB    32                // b-rows per block
#define RPW    16                // b-rows per wave
#define SPW    (RPW * KQ)        // 816 samples per wave
#define TPW    (SPW / 16)        // 51 tiles per wave

typedef __attribute__((ext_vector_type(8))) short short8;
typedef __attribute__((ext_vector_type(4))) float f32x4;

union S8U { short8 s8; unsigned u[4]; };

__device__ __forceinline__ unsigned short f2bf(float f) {
    __hip_bfloat16 t = __float2bfloat16(f);
    return *reinterpret_cast<unsigned short*>(&t);
}

#if defined(__gfx950__) && defined(__has_builtin)
#if __has_builtin(__builtin_amdgcn_cvt_pk_bf16_f32)
#define HAVE_PK_BF16 1
#endif
#endif

__device__ __forceinline__ unsigned pk_bf16(float lo, float hi) {
#ifdef HAVE_PK_BF16
    typedef __attribute__((ext_vector_type(2))) __bf16 bfv2;
    bfv2 r = __builtin_amdgcn_cvt_pk_bf16_f32(lo, hi);
    return *reinterpret_cast<unsigned*>(&r);
#else
    return (unsigned)f2bf(lo) | ((unsigned)f2bf(hi) << 16);
#endif
}

__launch_bounds__(BLK, 1)
__global__ void umnn_fused(const float* __restrict__ x,  const float* __restrict__ h,
                           const float* __restrict__ W1, const float* __restrict__ b1,
                           const float* __restrict__ W2, const float* __restrict__ b2,
                           const float* __restrict__ W3, const float* __restrict__ b3,
                           const float* __restrict__ W4, const float* __restrict__ b4,
                           float* __restrict__ out)
{
    __shared__ __align__(16) float hpL[RPB * HD];     // 16 KB block hpart
    __shared__ __align__(16) char  y2x[2][4096];      // per-wave Y2 scratch
    __shared__ __align__(16) float hshT[63 * 36];     // 9 KB h^T staging
    __shared__ float xL[RPB];
    __shared__ float zRow[RPB];
    __shared__ float sSteps[KQ], sCcw[KQ];
    __shared__ float red2[2];

    const int tid  = threadIdx.x;
    const int w    = tid >> 6;
    const int lane = tid & 63;
    const int q    = lane >> 4;
    const int lm   = lane & 15;
    const int swz  = lm & 7;
    const int rowBase = blockIdx.x * RPB;

    // ---- CC tables (validated r4 formula) ----
    if (tid < KQ) {
        const int j = tid;
        const float pi50 = 0.06283185307179586f;
        sSteps[j] = __cosf((float)j * pi50);
        float s = 0.0f;
        for (int i = 0; i <= 50; i += 2) {
            float Wi = (i == 0) ? 1.0f : 2.0f / (1.0f - (float)(i * i));
            float lam;
            if (j == 0) lam = 0.5f;
            else {
                int mp = (i * j) % 100;
                lam = __cosf((float)mp * pi50);
                if (j == 50) lam *= 0.5f;
            }
            s += (lam * 0.04f) * Wi;
        }
        sCcw[j] = s;
    }
    // ---- xmax scan (x: 64 KB, cache-resident) ----
    {
        const f32x4* x4 = (const f32x4*)x;
        float mx = -1e30f;
        for (int i = tid; i < B_N / 4; i += BLK) {
            f32x4 v = x4[i];
            mx = fmaxf(fmaxf(mx, fmaxf(v[0], v[1])), fmaxf(v[2], v[3]));
        }
        #pragma unroll
        for (int d = 32; d > 0; d >>= 1) mx = fmaxf(mx, __shfl_xor(mx, d));
        if (lane == 0) red2[w] = mx;
    }
    // ---- stage h^T for this block's 32 rows; init xL/zRow ----
    for (int i = tid; i < RPB * 63; i += BLK) {
        int r = i / 63, d = i - r * 63;
        hshT[d * 36 + r] = h[(rowBase) * 63 + i];
    }
    if (tid < RPB) { xL[tid] = x[rowBase + tid]; zRow[tid] = 0.0f; }
    __syncthreads();                                   // B1

    const float xmax = fmaxf(red2[0], red2[1]) + 10.0f;

    // ---- block hpart: thread tid = feature n, 32 row-accumulators ----
    {
        const int n = tid;
        float acc[RPB];
        const float b1v = b1[n];
        #pragma unroll
        for (int r = 0; r < RPB; ++r) acc[r] = b1v;
        const float* wr = W1 + n * IND + 1;
        #pragma unroll 1
        for (int d = 0; d < IND - 1; ++d) {
            float wv = wr[d];
            const float* ht = hshT + d * 36;
            #pragma unroll
            for (int rc = 0; rc < RPB / 4; ++rc) {
                f32x4 hv = *(const f32x4*)(ht + rc * 4);
                acc[rc * 4 + 0] = fmaf(wv, hv[0], acc[rc * 4 + 0]);
                acc[rc * 4 + 1] = fmaf(wv, hv[1], acc[rc * 4 + 1]);
                acc[rc * 4 + 2] = fmaf(wv, hv[2], acc[rc * 4 + 2]);
                acc[rc * 4 + 3] = fmaf(wv, hv[3], acc[rc * 4 + 3]);
            }
        }
        #pragma unroll
        for (int r = 0; r < RPB; ++r) hpL[r * HD + n] = acc[r];
    }

    // ---- wave-resident weights/biases (full 128 output features) ----
    float w1x[32];
    #pragma unroll
    for (int kk = 0; kk < 4; ++kk)
        #pragma unroll
        for (int j = 0; j < 8; ++j)
            w1x[kk * 8 + j] = W1[(kk * 32 + q * 8 + j) * IND];

    short8 W2A[8][4], W3A[8][4];
    f32x4  b2c[8], b3c[8], W4c[8];
    #pragma unroll
    for (int nt = 0; nt < 8; ++nt) {
        #pragma unroll
        for (int kk = 0; kk < 4; ++kk) {
            const float* p2 = W2 + (nt * 16 + lm) * HD + kk * 32 + q * 8;
            const float* p3 = W3 + (nt * 16 + lm) * HD + kk * 32 + q * 8;
            S8U a2, a3;
            #pragma unroll
            for (int j = 0; j < 4; ++j) {
                a2.u[j] = pk_bf16(p2[2 * j], p2[2 * j + 1]);
                a3.u[j] = pk_bf16(p3[2 * j], p3[2 * j + 1]);
            }
            W2A[nt][kk] = a2.s8; W3A[nt][kk] = a3.s8;
        }
        b2c[nt] = *(const f32x4*)(b2 + nt * 16 + q * 4);
        b3c[nt] = *(const f32x4*)(b3 + nt * 16 + q * 4);
        W4c[nt] = *(const f32x4*)(W4 + nt * 16 + q * 4);
    }
    const float b4v = b4[0];
    char* myY2 = y2x[w];
    __syncthreads();                                   // B2 (hpL ready)

    const int S0 = blockIdx.x * (RPB * KQ) + w * SPW;

    // ================= per-wave tile loop: NO barriers =================
    #pragma unroll 1
    for (int tt = 0; tt < TPW; ++tt) {
        const int s   = S0 + tt * 16 + lm;             // lane's sample
        const unsigned row = (unsigned)s / KQ;
        const int k   = s - (int)row * KQ;
        const int rl  = (int)row - rowBase;
        const float x0 = xL[rl];
        const float X  = fmaf((xmax - x0) * 0.5f, sSteps[k] + 1.0f, x0);

        // ---- Y1 B-frags in registers ----
        short8 Y1[4];
        #pragma unroll
        for (int kk = 0; kk < 4; ++kk) {
            const float* hp = hpL + rl * HD + kk * 32 + q * 8;
            f32x4 ha = *(const f32x4*)hp;
            f32x4 hb = *(const f32x4*)(hp + 4);
            S8U u;
            u.u[0] = pk_bf16(fmaxf(fmaf(X, w1x[kk*8+0], ha[0]), 0.f),
                             fmaxf(fmaf(X, w1x[kk*8+1], ha[1]), 0.f));
            u.u[1] = pk_bf16(fmaxf(fmaf(X, w1x[kk*8+2], ha[2]), 0.f),
                             fmaxf(fmaf(X, w1x[kk*8+3], ha[3]), 0.f));
            u.u[2] = pk_bf16(fmaxf(fmaf(X, w1x[kk*8+4], hb[0]), 0.f),
                             fmaxf(fmaf(X, w1x[kk*8+5], hb[1]), 0.f));
            u.u[3] = pk_bf16(fmaxf(fmaf(X, w1x[kk*8+6], hb[2]), 0.f),
                             fmaxf(fmaf(X, w1x[kk*8+7], hb[3]), 0.f));
            Y1[kk] = u.s8;
        }

        // ---- layer 2: 32 MFMA, C in registers ----
        f32x4 C[8];
        #pragma unroll
        for (int nt = 0; nt < 8; ++nt) C[nt] = b2c[nt];
        #pragma unroll
        for (int kk = 0; kk < 4; ++kk)
            #pragma unroll
            for (int nt = 0; nt < 8; ++nt)
                C[nt] = __builtin_amdgcn_mfma_f32_16x16x32_bf16(W2A[nt][kk], Y1[kk], C[nt], 0, 0, 0);

        // ---- Y2: wave-private LDS round-trip (no barrier) ----
        #pragma unroll
        for (int nt = 0; nt < 8; ++nt) {
            unsigned lo = pk_bf16(fmaxf(C[nt][0], 0.f), fmaxf(C[nt][1], 0.f));
            unsigned hi = pk_bf16(fmaxf(C[nt][2], 0.f), fmaxf(C[nt][3], 0.f));
            *(int2*)(myY2 + lm * 256 + (((2*nt + (q>>1)) ^ swz) << 4) + ((q & 1) << 3))
                = make_int2((int)lo, (int)hi);
        }
        short8 Y2[4];
        #pragma unroll
        for (int kk = 0; kk < 4; ++kk)
            Y2[kk] = *(const short8*)(myY2 + lm * 256 + (((kk*4 + q) ^ swz) << 4));

        // ---- layer 3 ----
        #pragma unroll
        for (int nt = 0; nt < 8; ++nt) C[nt] = b3c[nt];
        #pragma unroll
        for (int kk = 0; kk < 4; ++kk)
            #pragma unroll
            for (int nt = 0; nt < 8; ++nt)
                C[nt] = __builtin_amdgcn_mfma_f32_16x16x32_bf16(W3A[nt][kk], Y2[kk], C[nt], 0, 0, 0);

        // ---- layer 4 + elu + ccw + segmented row accumulation ----
        float p = 0.f;
        #pragma unroll
        for (int nt = 0; nt < 8; ++nt) {
            p = fmaf(fmaxf(C[nt][0], 0.f), W4c[nt][0], p);
            p = fmaf(fmaxf(C[nt][1], 0.f), W4c[nt][1], p);
            p = fmaf(fmaxf(C[nt][2], 0.f), W4c[nt][2], p);
            p = fmaf(fmaxf(C[nt][3], 0.f), W4c[nt][3], p);
        }
        p += __shfl_xor(p, 16);
        p += __shfl_xor(p, 32);                        // q-reduce: y4 at all q
        float y4 = p + b4v;
        float f  = (y4 > 0.f) ? (y4 + 1.f) : __expf(y4);
        float v  = (lane < 16) ? f * sCcw[k] : 0.f;

        const int s0t = S0 + tt * 16;
        const int r0  = s0t / KQ;
        const bool two = ((s0t + 15) / KQ) > r0;
        float t0 = ((int)row == r0) ? v : 0.f;
        t0 += __shfl_xor(t0, 1); t0 += __shfl_xor(t0, 2);
        t0 += __shfl_xor(t0, 4); t0 += __shfl_xor(t0, 8);
        if (two) {
            float t1 = ((int)row > r0) ? v : 0.f;
            t1 += __shfl_xor(t1, 1); t1 += __shfl_xor(t1, 2);
            t1 += __shfl_xor(t1, 4); t1 += __shfl_xor(t1, 8);
            if (lane == 0) {
                atomicAdd(&zRow[r0 - rowBase], t0);
                atomicAdd(&zRow[r0 + 1 - rowBase], t1);
            }
        } else if (lane == 0) {
            atomicAdd(&zRow[r0 - rowBase], t0);
        }
    }

    // ---- wave-private epilogue: plain global stores (all rows covered) ----
    if (lane < RPW) {
        int rl = w * RPW + lane;
        out[rowBase + rl] = zRow[rl] * (xmax - xL[rl]) * 0.5f;
    }
}

// ---------------------------------------------------------------------------
extern "C" void kernel_launch(void* const* d_in, const int* in_sizes, int n_in,
                              void* d_out, int out_size, void* d_ws, size_t ws_size,
                              hipStream_t stream)
{
    const float* x  = (const float*)d_in[0];
    const float* h  = (const float*)d_in[1];
    const float* W1 = (const float*)d_in[2];
    const float* b1 = (const float*)d_in[3];
    const float* W2 = (const float*)d_in[4];
    const float* b2 = (const float*)d_in[5];
    const float* W3 = (const float*)d_in[6];
    const float* b3 = (const float*)d_in[7];
    const float* W4 = (const float*)d_in[8];
    const float* b4 = (const float*)d_in[9];
    float* out = (float*)d_out;

    umnn_fused<<<GRID, BLK, 0, stream>>>(x, h, W1, b1, W2, b2, W3, b3,
                                         W4, b4, out);
}

// Round 7
// 186.436 us; speedup vs baseline: 1.6456x; 1.1322x over previous
//
#include <hip/hip_runtime.h>
#include <hip/hip_bf16.h>
#include <math.h>

// ---------------------------------------------------------------------------
// Round 7: r6 architecture (zero-barrier loop, register-resident W2/W3,
// wave-owns-16-rows) + latency attack. r6 counters: MfmaUtil 14 + VALUBusy 37
// => ~49% stall at 1 wave/SIMD (structural: ~370 regs/wave). Fixes:
//   1. DEFERRED EPILOGUE: per tile only 2 q-reduce shuffles + one
//      ds_write_b32 of the 16 layer-4 partials into wave-private vs[816];
//      expf + ccw + segmented row-reduce + stores happen ONCE after the loop.
//      (removes ~400 serial cyc/tile: 8-shuffle chain, expf, LDS atomics)
//   2. Y1 SOFTWARE PIPELINE: tile t+1's B-fragments (VALU + hpL reads,
//      independent) computed inside tile t's body between Y2-write and
//      Y2-read, filling the MFMA-chain and LDS round-trip latency.
// Numerics: identical rounding chain (absmax 0.125 vs thr 0.4725); only the
// final per-row fp32 summation order changes (~1e-6).
// ---------------------------------------------------------------------------

#define B_N    16384
#define KQ     51
#define HD     128
#define IND    64
#define BLK    128               // 2 waves
#define GRID   512
#define RPB    32                // b-rows per block
#define RPW    16                // b-rows per wave
#define SPW    (RPW * KQ)        // 816 samples per wave
#define TPW    (SPW / 16)        // 51 tiles per wave

typedef __attribute__((ext_vector_type(8))) short short8;
typedef __attribute__((ext_vector_type(4))) float f32x4;

union S8U { short8 s8; unsigned u[4]; };

__device__ __forceinline__ unsigned short f2bf(float f) {
    __hip_bfloat16 t = __float2bfloat16(f);
    return *reinterpret_cast<unsigned short*>(&t);
}

#if defined(__gfx950__) && defined(__has_builtin)
#if __has_builtin(__builtin_amdgcn_cvt_pk_bf16_f32)
#define HAVE_PK_BF16 1
#endif
#endif

__device__ __forceinline__ unsigned pk_bf16(float lo, float hi) {
#ifdef HAVE_PK_BF16
    typedef __attribute__((ext_vector_type(2))) __bf16 bfv2;
    bfv2 r = __builtin_amdgcn_cvt_pk_bf16_f32(lo, hi);
    return *reinterpret_cast<unsigned*>(&r);
#else
    return (unsigned)f2bf(lo) | ((unsigned)f2bf(hi) << 16);
#endif
}

__launch_bounds__(BLK, 1)
__global__ void umnn_fused(const float* __restrict__ x,  const float* __restrict__ h,
                           const float* __restrict__ W1, const float* __restrict__ b1,
                           const float* __restrict__ W2, const float* __restrict__ b2,
                           const float* __restrict__ W3, const float* __restrict__ b3,
                           const float* __restrict__ W4, const float* __restrict__ b4,
                           float* __restrict__ out)
{
    __shared__ __align__(16) float hpL[RPB * HD];     // 16 KB block hpart
    __shared__ __align__(16) char  y2x[2][4096];      // per-wave Y2 scratch
    __shared__ __align__(16) float hshT[63 * 36];     // 9 KB h^T staging
    __shared__ float vs[2][SPW + 16];                 // per-wave y4-partials
    __shared__ float xL[RPB];
    __shared__ float sSteps[KQ], sCcw[KQ];
    __shared__ float red2[2];

    const int tid  = threadIdx.x;
    const int w    = tid >> 6;
    const int lane = tid & 63;
    const int q    = lane >> 4;
    const int lm   = lane & 15;
    const int swz  = lm & 7;
    const int rowBase = blockIdx.x * RPB;

    // ---- CC tables (validated r4 formula) ----
    if (tid < KQ) {
        const int j = tid;
        const float pi50 = 0.06283185307179586f;
        sSteps[j] = __cosf((float)j * pi50);
        float s = 0.0f;
        for (int i = 0; i <= 50; i += 2) {
            float Wi = (i == 0) ? 1.0f : 2.0f / (1.0f - (float)(i * i));
            float lam;
            if (j == 0) lam = 0.5f;
            else {
                int mp = (i * j) % 100;
                lam = __cosf((float)mp * pi50);
                if (j == 50) lam *= 0.5f;
            }
            s += (lam * 0.04f) * Wi;
        }
        sCcw[j] = s;
    }
    // ---- xmax scan (x: 64 KB, cache-resident) ----
    {
        const f32x4* x4 = (const f32x4*)x;
        float mx = -1e30f;
        for (int i = tid; i < B_N / 4; i += BLK) {
            f32x4 v = x4[i];
            mx = fmaxf(fmaxf(mx, fmaxf(v[0], v[1])), fmaxf(v[2], v[3]));
        }
        #pragma unroll
        for (int d = 32; d > 0; d >>= 1) mx = fmaxf(mx, __shfl_xor(mx, d));
        if (lane == 0) red2[w] = mx;
    }
    // ---- stage h^T for this block's 32 rows; init xL ----
    for (int i = tid; i < RPB * 63; i += BLK) {
        int r = i / 63, d = i - r * 63;
        hshT[d * 36 + r] = h[(rowBase) * 63 + i];
    }
    if (tid < RPB) xL[tid] = x[rowBase + tid];
    __syncthreads();                                   // B1

    const float xmax = fmaxf(red2[0], red2[1]) + 10.0f;

    // ---- block hpart: thread tid = feature n, 32 row-accumulators ----
    {
        const int n = tid;
        float acc[RPB];
        const float b1v = b1[n];
        #pragma unroll
        for (int r = 0; r < RPB; ++r) acc[r] = b1v;
        const float* wr = W1 + n * IND + 1;
        #pragma unroll 1
        for (int d = 0; d < IND - 1; ++d) {
            float wv = wr[d];
            const float* ht = hshT + d * 36;
            #pragma unroll
            for (int rc = 0; rc < RPB / 4; ++rc) {
                f32x4 hv = *(const f32x4*)(ht + rc * 4);
                acc[rc * 4 + 0] = fmaf(wv, hv[0], acc[rc * 4 + 0]);
                acc[rc * 4 + 1] = fmaf(wv, hv[1], acc[rc * 4 + 1]);
                acc[rc * 4 + 2] = fmaf(wv, hv[2], acc[rc * 4 + 2]);
                acc[rc * 4 + 3] = fmaf(wv, hv[3], acc[rc * 4 + 3]);
            }
        }
        #pragma unroll
        for (int r = 0; r < RPB; ++r) hpL[r * HD + n] = acc[r];
    }

    // ---- wave-resident weights/biases ----
    float w1x[32];
    #pragma unroll
    for (int kk = 0; kk < 4; ++kk)
        #pragma unroll
        for (int j = 0; j < 8; ++j)
            w1x[kk * 8 + j] = W1[(kk * 32 + q * 8 + j) * IND];

    short8 W2A[8][4], W3A[8][4];
    f32x4  b2c[8], b3c[8], W4c[8];
    #pragma unroll
    for (int nt = 0; nt < 8; ++nt) {
        #pragma unroll
        for (int kk = 0; kk < 4; ++kk) {
            const float* p2 = W2 + (nt * 16 + lm) * HD + kk * 32 + q * 8;
            const float* p3 = W3 + (nt * 16 + lm) * HD + kk * 32 + q * 8;
            S8U a2, a3;
            #pragma unroll
            for (int j = 0; j < 4; ++j) {
                a2.u[j] = pk_bf16(p2[2 * j], p2[2 * j + 1]);
                a3.u[j] = pk_bf16(p3[2 * j], p3[2 * j + 1]);
            }
            W2A[nt][kk] = a2.s8; W3A[nt][kk] = a3.s8;
        }
        b2c[nt] = *(const f32x4*)(b2 + nt * 16 + q * 4);
        b3c[nt] = *(const f32x4*)(b3 + nt * 16 + q * 4);
        W4c[nt] = *(const f32x4*)(W4 + nt * 16 + q * 4);
    }
    const float b4v = b4[0];
    char*  myY2 = y2x[w];
    float* vsW  = vs[w];
    __syncthreads();                                   // B2 (hpL ready)

    const int S0 = blockIdx.x * (RPB * KQ) + w * SPW;

    // Y1 builder for tile tt (tt may overshoot by 1 on the prefetch; rl is
    // clamped so LDS reads stay in-bounds — the result is discarded).
    auto computeY1 = [&](int tt, short8* Y) {
        const int s   = S0 + tt * 16 + lm;
        const unsigned row = (unsigned)s / KQ;
        const int k   = s - (int)row * KQ;
        const int rl  = min((int)row - rowBase, RPB - 1);
        const float x0 = xL[rl];
        const float X  = fmaf((xmax - x0) * 0.5f, sSteps[k] + 1.0f, x0);
        #pragma unroll
        for (int kk = 0; kk < 4; ++kk) {
            const float* hp = hpL + rl * HD + kk * 32 + q * 8;
            f32x4 ha = *(const f32x4*)hp;
            f32x4 hb = *(const f32x4*)(hp + 4);
            S8U u;
            u.u[0] = pk_bf16(fmaxf(fmaf(X, w1x[kk*8+0], ha[0]), 0.f),
                             fmaxf(fmaf(X, w1x[kk*8+1], ha[1]), 0.f));
            u.u[1] = pk_bf16(fmaxf(fmaf(X, w1x[kk*8+2], ha[2]), 0.f),
                             fmaxf(fmaf(X, w1x[kk*8+3], ha[3]), 0.f));
            u.u[2] = pk_bf16(fmaxf(fmaf(X, w1x[kk*8+4], hb[0]), 0.f),
                             fmaxf(fmaf(X, w1x[kk*8+5], hb[1]), 0.f));
            u.u[3] = pk_bf16(fmaxf(fmaf(X, w1x[kk*8+6], hb[2]), 0.f),
                             fmaxf(fmaf(X, w1x[kk*8+7], hb[3]), 0.f));
            Y[kk] = u.s8;
        }
    };

    short8 Y1c[4], Y1n[4];
    computeY1(0, Y1c);

    // ================= per-wave tile loop: NO barriers =================
    #pragma unroll 1
    for (int tt = 0; tt < TPW; ++tt) {
        // ---- layer 2: 32 MFMA, C in registers ----
        f32x4 C[8];
        #pragma unroll
        for (int nt = 0; nt < 8; ++nt) C[nt] = b2c[nt];
        #pragma unroll
        for (int kk = 0; kk < 4; ++kk)
            #pragma unroll
            for (int nt = 0; nt < 8; ++nt)
                C[nt] = __builtin_amdgcn_mfma_f32_16x16x32_bf16(W2A[nt][kk], Y1c[kk], C[nt], 0, 0, 0);

        // ---- Y2 write (wave-private, no barrier) ----
        #pragma unroll
        for (int nt = 0; nt < 8; ++nt) {
            unsigned lo = pk_bf16(fmaxf(C[nt][0], 0.f), fmaxf(C[nt][1], 0.f));
            unsigned hi = pk_bf16(fmaxf(C[nt][2], 0.f), fmaxf(C[nt][3], 0.f));
            *(int2*)(myY2 + lm * 256 + (((2*nt + (q>>1)) ^ swz) << 4) + ((q & 1) << 3))
                = make_int2((int)lo, (int)hi);
        }

        // ---- pipeline: next tile's Y1 (independent VALU + hpL reads) ----
        computeY1(tt + 1, Y1n);

        // ---- Y2 read ----
        short8 Y2[4];
        #pragma unroll
        for (int kk = 0; kk < 4; ++kk)
            Y2[kk] = *(const short8*)(myY2 + lm * 256 + (((kk*4 + q) ^ swz) << 4));

        // ---- layer 3 ----
        #pragma unroll
        for (int nt = 0; nt < 8; ++nt) C[nt] = b3c[nt];
        #pragma unroll
        for (int kk = 0; kk < 4; ++kk)
            #pragma unroll
            for (int nt = 0; nt < 8; ++nt)
                C[nt] = __builtin_amdgcn_mfma_f32_16x16x32_bf16(W3A[nt][kk], Y2[kk], C[nt], 0, 0, 0);

        // ---- layer 4 partial: q-reduce only, defer the rest ----
        float p = 0.f;
        #pragma unroll
        for (int nt = 0; nt < 8; ++nt) {
            p = fmaf(fmaxf(C[nt][0], 0.f), W4c[nt][0], p);
            p = fmaf(fmaxf(C[nt][1], 0.f), W4c[nt][1], p);
            p = fmaf(fmaxf(C[nt][2], 0.f), W4c[nt][2], p);
            p = fmaf(fmaxf(C[nt][3], 0.f), W4c[nt][3], p);
        }
        p += __shfl_xor(p, 16);
        p += __shfl_xor(p, 32);
        if (lane < 16) vsW[tt * 16 + lm] = p;

        #pragma unroll
        for (int kk = 0; kk < 4; ++kk) Y1c[kk] = Y1n[kk];
    }

    // ---- deferred epilogue (wave-private, once): elu+ccw+row-reduce ----
    {
        const int r   = lane >> 2;          // wave-local row 0..15
        const int sub = lane & 3;
        float a = 0.f;
        #pragma unroll 1
        for (int j = 0; j < 13; ++j) {
            int k = sub + 4 * j;
            if (k < KQ) {
                float y4 = vsW[r * KQ + k] + b4v;
                float f  = (y4 > 0.f) ? (y4 + 1.f) : __expf(y4);
                a = fmaf(f, sCcw[k], a);
            }
        }
        a += __shfl_xor(a, 1);
        a += __shfl_xor(a, 2);
        if (sub == 0) {
            int rl = w * RPW + r;
            out[rowBase + rl] = a * (xmax - xL[rl]) * 0.5f;
        }
    }
}

// ---------------------------------------------------------------------------
extern "C" void kernel_launch(void* const* d_in, const int* in_sizes, int n_in,
                              void* d_out, int out_size, void* d_ws, size_t ws_size,
                              hipStream_t stream)
{
    const float* x  = (const float*)d_in[0];
    const float* h  = (const float*)d_in[1];
    const float* W1 = (const float*)d_in[2];
    const float* b1 = (const float*)d_in[3];
    const float* W2 = (const float*)d_in[4];
    const float* b2 = (const float*)d_in[5];
    const float* W3 = (const float*)d_in[6];
    const float* b3 = (const float*)d_in[7];
    const float* W4 = (const float*)d_in[8];
    const float* b4 = (const float*)d_in[9];
    float* out = (float*)d_out;

    umnn_fused<<<GRID, BLK, 0, stream>>>(x, h, W1, b1, W2, b2, W3, b3,
                                         W4, b4, out);
}